// Round 2
// baseline (331.558 us; speedup 1.0000x reference)
//
#include <hip/hip_runtime.h>
#include <hip/hip_bf16.h>
#include <stdint.h>

#define BB 4
#define TT 2048
#define DD 1024
#define HH 16
#define DKK 64

typedef unsigned short u16;
typedef unsigned int u32;
typedef __bf16 bf16_t;
typedef bf16_t bf16x8 __attribute__((ext_vector_type(8)));
typedef float f32x4 __attribute__((ext_vector_type(4)));

__device__ __forceinline__ float bf2f(u16 u) {
    u32 x = ((u32)u) << 16;
    float f;
    __builtin_memcpy(&f, &x, 4);
    return f;
}
__device__ __forceinline__ u16 f2bf(float f) {
    u32 x;
    __builtin_memcpy(&x, &f, 4);
    x += 0x7fffu + ((x >> 16) & 1u);  // RNE truncate (no NaN inputs here)
    return (u16)(x >> 16);
}

// async global->LDS, 16B per lane; l must be the WAVE-UNIFORM base (lane*16 added by HW)
__device__ __forceinline__ void gll16(const u16* g, u16* l) {
    __builtin_amdgcn_global_load_lds((const __attribute__((address_space(1))) u32*)g,
                                     (__attribute__((address_space(3))) u32*)l, 16, 0, 0);
}

// ---------------------------------------------------------------- casts
__global__ void cast_f32_bf16(const float* __restrict__ in, u16* __restrict__ out, int n) {
    int i = (blockIdx.x * blockDim.x + threadIdx.x) * 4;
    int stride = gridDim.x * blockDim.x * 4;
    for (; i < n; i += stride) {
        float4 v = *reinterpret_cast<const float4*>(in + i);
        uint2 pk;
        pk.x = (u32)f2bf(v.x) | ((u32)f2bf(v.y) << 16);
        pk.y = (u32)f2bf(v.z) | ((u32)f2bf(v.w) << 16);
        *reinterpret_cast<uint2*>(out + i) = pk;
    }
}

// ---------------------------------------------------------------- GEMM core
// C[m][n] = sum_k A[m][k] * W[n][k]   (TN), M-tile 128, N-tile 128, BK=32
// A: [M][1024] bf16 row-major, W: [1024][1024] bf16 row-major
__device__ __forceinline__ void gemm_128_mainloop(const u16* __restrict__ A,
                                                  const u16* __restrict__ W,
                                                  u16* As, u16* Bs,
                                                  int m0, int n0, f32x4 acc[4][4]) {
    const int tid = threadIdx.x;
    const int lane = tid & 63;
    const int wid = tid >> 6;
    const int wr = (wid >> 1) * 64, wc = (wid & 1) * 64;
    const int l15 = lane & 15, l4 = lane >> 4;

    const f32x4 z4 = {0.f, 0.f, 0.f, 0.f};
#pragma unroll
    for (int i = 0; i < 4; i++)
#pragma unroll
        for (int j = 0; j < 4; j++) acc[i][j] = z4;

    // staging: tile is 128 rows x 32 cols bf16 = 8 KB = 512 chunks of 16B.
    // chunk d = iss*256 + tid; r = d>>2 (4 chunks/row), cc = d&3.
    const int r0 = tid >> 2;
    const int c0 = (tid & 3) * 8;  // element offset within row

    for (int k0 = 0; k0 < DD; k0 += 32) {
        __syncthreads();
        gll16(A + (m0 + r0) * DD + k0 + c0, As + (wid * 64) * 8);
        gll16(A + (m0 + 64 + r0) * DD + k0 + c0, As + (256 + wid * 64) * 8);
        gll16(W + (n0 + r0) * DD + k0 + c0, Bs + (wid * 64) * 8);
        gll16(W + (n0 + 64 + r0) * DD + k0 + c0, Bs + (256 + wid * 64) * 8);
        asm volatile("s_waitcnt vmcnt(0)" ::: "memory");
        __syncthreads();

        bf16x8 af[4], bfr[4];
#pragma unroll
        for (int mi = 0; mi < 4; mi++)
            af[mi] = *reinterpret_cast<const bf16x8*>(As + (wr + mi * 16 + l15) * 32 + l4 * 8);
#pragma unroll
        for (int ni = 0; ni < 4; ni++)
            bfr[ni] = *reinterpret_cast<const bf16x8*>(Bs + (wc + ni * 16 + l15) * 32 + l4 * 8);
#pragma unroll
        for (int mi = 0; mi < 4; mi++)
#pragma unroll
            for (int ni = 0; ni < 4; ni++)
                acc[mi][ni] =
                    __builtin_amdgcn_mfma_f32_16x16x32_bf16(af[mi], bfr[ni], acc[mi][ni], 0, 0, 0);
    }
}

// z=0: Q  -> [b][h][t][dk] bf16
// z=1: K  -> [b][h][t][dk] bf16
// z=2: V  -> [b][h][dk][t] bf16 (transposed for PV B-fragments)
__global__ __launch_bounds__(256) void gemm_qkv(const u16* __restrict__ xb,
                                                const u16* __restrict__ wq,
                                                const u16* __restrict__ wk,
                                                const u16* __restrict__ wv,
                                                u16* __restrict__ Qo, u16* __restrict__ Ko,
                                                u16* __restrict__ Vto) {
    __shared__ u16 As[128 * 32];
    __shared__ u16 Bs[128 * 32];
    const int z = blockIdx.z;
    const u16* W = (z == 0) ? wq : (z == 1) ? wk : wv;
    u16* dst = (z == 0) ? Qo : (z == 1) ? Ko : Vto;
    const int m0 = blockIdx.x * 128, n0 = blockIdx.y * 128;

    f32x4 acc[4][4];
    gemm_128_mainloop(xb, W, As, Bs, m0, n0, acc);

    const int lane = threadIdx.x & 63, wid = threadIdx.x >> 6;
    const int wr = (wid >> 1) * 64, wc = (wid & 1) * 64;
    const int l15 = lane & 15, l4 = lane >> 4;
#pragma unroll
    for (int mi = 0; mi < 4; mi++)
#pragma unroll
        for (int ni = 0; ni < 4; ni++)
#pragma unroll
            for (int j = 0; j < 4; j++) {
                int m = m0 + wr + mi * 16 + l4 * 4 + j;  // token
                int n = n0 + wc + ni * 16 + l15;          // feature e = h*64+dk
                int b = m >> 11, t = m & (TT - 1);
                int h = n >> 6, dk = n & 63;
                u16 v = f2bf(acc[mi][ni][j]);
                if (z < 2)
                    dst[((b * HH + h) * TT + t) * DKK + dk] = v;
                else
                    dst[((b * HH + h) * DKK + dk) * TT + t] = v;
            }
}

__global__ __launch_bounds__(256) void gemm_out(const u16* __restrict__ ctx,
                                                const u16* __restrict__ wo,
                                                float* __restrict__ out) {
    __shared__ u16 As[128 * 32];
    __shared__ u16 Bs[128 * 32];
    const int m0 = blockIdx.x * 128, n0 = blockIdx.y * 128;
    f32x4 acc[4][4];
    gemm_128_mainloop(ctx, wo, As, Bs, m0, n0, acc);

    const int lane = threadIdx.x & 63, wid = threadIdx.x >> 6;
    const int wr = (wid >> 1) * 64, wc = (wid & 1) * 64;
    const int l15 = lane & 15, l4 = lane >> 4;
#pragma unroll
    for (int mi = 0; mi < 4; mi++)
#pragma unroll
        for (int ni = 0; ni < 4; ni++)
#pragma unroll
            for (int j = 0; j < 4; j++) {
                int m = m0 + wr + mi * 16 + l4 * 4 + j;
                int n = n0 + wc + ni * 16 + l15;
                out[m * DD + n] = acc[mi][ni][j];
            }
}

// ---------------------------------------------------------------- flash attention
// grid: (T/128, B*H). 4 waves/block; wave w owns q rows q0+w*32 .. +31.
// Q,K: [bh][t][64] bf16 ; Vt: [bh][64][t] bf16 ; ctx out: [b][t][1024] bf16
__global__ __launch_bounds__(256) void attn_fwd(const u16* __restrict__ Qg,
                                                const u16* __restrict__ Kg,
                                                const u16* __restrict__ Vtg,
                                                u16* __restrict__ ctx) {
    __shared__ u16 Kld[64 * 64];    // [k][dk], rows 128B, chunk-swizzled cc^= r&7
    __shared__ u16 Vld[64 * 64];    // [dk][k], rows 128B, swizzled
    __shared__ u16 Pld[4][32 * 64]; // per-wave [q][k], rows 128B, swizzled

    const int tid = threadIdx.x;
    const int lane = tid & 63, wid = tid >> 6;
    const int l15 = lane & 15, l4 = lane >> 4;
    const int bh = blockIdx.y;
    const int q0 = blockIdx.x * 128;
    const int qbase = q0 + wid * 32;

    const u16* Qb = Qg + (size_t)bh * TT * DKK;
    const u16* Kb = Kg + (size_t)bh * TT * DKK;
    const u16* Vb = Vtg + (size_t)bh * DKK * TT;

    // Q fragments, pre-scaled by 1/sqrt(dk)=0.125
    bf16x8 qf[2][2];
#pragma unroll
    for (int rf = 0; rf < 2; rf++)
#pragma unroll
        for (int kc = 0; kc < 2; kc++) {
            const u16* p = Qb + (qbase + rf * 16 + l15) * DKK + kc * 32 + l4 * 8;
            union { uint4 u; u16 h[8]; } cv;
            cv.u = *reinterpret_cast<const uint4*>(p);
            u16 o[8];
#pragma unroll
            for (int e = 0; e < 8; e++) o[e] = f2bf(bf2f(cv.h[e]) * 0.125f);
            __builtin_memcpy(&qf[rf][kc], o, 16);
        }

    f32x4 acc[2][4];
    const f32x4 z4 = {0.f, 0.f, 0.f, 0.f};
#pragma unroll
    for (int rf = 0; rf < 2; rf++)
#pragma unroll
        for (int cf = 0; cf < 4; cf++) acc[rf][cf] = z4;
    float mrow[2][4], lrow[2][4];
#pragma unroll
    for (int rf = 0; rf < 2; rf++)
#pragma unroll
        for (int j = 0; j < 4; j++) { mrow[rf][j] = -__builtin_huge_valf(); lrow[rf][j] = 0.f; }

    u16* Pw = &Pld[wid][0];
    const int nkt = q0 / 64 + 2;

    for (int kt = 0; kt < nkt; kt++) {
        __syncthreads();
        {   // stage K (8KB) + Vt (8KB): 2 issues each, source pre-swizzled
            int r = tid >> 3, cc = tid & 7;
            int cs = cc ^ (r & 7);
            gll16(Kb + (kt * 64 + r) * DKK + cs * 8, Kld + (wid * 64) * 8);
            gll16(Vb + r * TT + kt * 64 + cs * 8, Vld + (wid * 64) * 8);
            int r1 = 32 + r;
            int cs1 = cc ^ (r1 & 7);
            gll16(Kb + (kt * 64 + r1) * DKK + cs1 * 8, Kld + (256 + wid * 64) * 8);
            gll16(Vb + r1 * TT + kt * 64 + cs1 * 8, Vld + (256 + wid * 64) * 8);
        }
        asm volatile("s_waitcnt vmcnt(0)" ::: "memory");
        __syncthreads();

        // S = Q K^T  : S[q][k], q rows = qbase+rf*16+(l4*4+j), k cols = kt*64+cf*16+l15
        f32x4 s[2][4];
#pragma unroll
        for (int rf = 0; rf < 2; rf++)
#pragma unroll
            for (int cf = 0; cf < 4; cf++) s[rf][cf] = z4;
#pragma unroll
        for (int kc = 0; kc < 2; kc++) {
#pragma unroll
            for (int cf = 0; cf < 4; cf++) {
                int kr = cf * 16 + l15;
                int cw = (l4 + kc * 4) ^ (kr & 7);
                bf16x8 kf = *reinterpret_cast<const bf16x8*>(
                    reinterpret_cast<const char*>(Kld) + kr * 128 + cw * 16);
#pragma unroll
                for (int rf = 0; rf < 2; rf++)
                    s[rf][cf] = __builtin_amdgcn_mfma_f32_16x16x32_bf16(qf[rf][kc], kf, s[rf][cf], 0, 0, 0);
            }
        }

        // causal mask (also handles fully-masked tiles for low waves)
        if (kt * 64 + 63 > qbase) {
#pragma unroll
            for (int rf = 0; rf < 2; rf++)
#pragma unroll
                for (int cf = 0; cf < 4; cf++)
#pragma unroll
                    for (int j = 0; j < 4; j++) {
                        int kk = kt * 64 + cf * 16 + l15;
                        int qq = qbase + rf * 16 + l4 * 4 + j;
                        if (kk > qq) s[rf][cf][j] = -__builtin_huge_valf();
                    }
        }

        // online softmax
#pragma unroll
        for (int rf = 0; rf < 2; rf++) {
            float pm[4];
#pragma unroll
            for (int j = 0; j < 4; j++)
                pm[j] = fmaxf(fmaxf(s[rf][0][j], s[rf][1][j]), fmaxf(s[rf][2][j], s[rf][3][j]));
#pragma unroll
            for (int j = 0; j < 4; j++) {
                pm[j] = fmaxf(pm[j], __shfl_xor(pm[j], 1));
                pm[j] = fmaxf(pm[j], __shfl_xor(pm[j], 2));
                pm[j] = fmaxf(pm[j], __shfl_xor(pm[j], 4));
                pm[j] = fmaxf(pm[j], __shfl_xor(pm[j], 8));
            }
#pragma unroll
            for (int j = 0; j < 4; j++) {
                float mn = fmaxf(mrow[rf][j], pm[j]);
                float sc = __expf(mrow[rf][j] - mn);  // -inf - finite -> 0
                mrow[rf][j] = mn;
                float rs = 0.f;
#pragma unroll
                for (int cf = 0; cf < 4; cf++) {
                    float p = __expf(s[rf][cf][j] - mn);
                    s[rf][cf][j] = p;
                    rs += p;
                }
                rs += __shfl_xor(rs, 1);
                rs += __shfl_xor(rs, 2);
                rs += __shfl_xor(rs, 4);
                rs += __shfl_xor(rs, 8);
                lrow[rf][j] = lrow[rf][j] * sc + rs;
#pragma unroll
                for (int cf = 0; cf < 4; cf++) acc[rf][cf][j] *= sc;
            }
        }

        // P -> per-wave LDS (swizzled), then PV
#pragma unroll
        for (int rf = 0; rf < 2; rf++)
#pragma unroll
            for (int cf = 0; cf < 4; cf++)
#pragma unroll
                for (int j = 0; j < 4; j++) {
                    int r = rf * 16 + l4 * 4 + j;
                    int col = cf * 16 + l15;
                    int byte = r * 128 + (((col >> 3) ^ (r & 7)) << 4) + (col & 7) * 2;
                    *reinterpret_cast<u16*>(reinterpret_cast<char*>(Pw) + byte) =
                        f2bf(s[rf][cf][j]);
                }
        asm volatile("s_waitcnt lgkmcnt(0)" ::: "memory");

#pragma unroll
        for (int kc = 0; kc < 2; kc++) {
            bf16x8 pa[2];
#pragma unroll
            for (int rf = 0; rf < 2; rf++) {
                int r = rf * 16 + l15;
                int cw = (l4 + kc * 4) ^ (r & 7);
                pa[rf] = *reinterpret_cast<const bf16x8*>(
                    reinterpret_cast<const char*>(Pw) + r * 128 + cw * 16);
            }
#pragma unroll
            for (int cf = 0; cf < 4; cf++) {
                int vr = cf * 16 + l15;
                int vw = (l4 + kc * 4) ^ (vr & 7);
                bf16x8 vf = *reinterpret_cast<const bf16x8*>(
                    reinterpret_cast<const char*>(Vld) + vr * 128 + vw * 16);
#pragma unroll
                for (int rf = 0; rf < 2; rf++)
                    acc[rf][cf] = __builtin_amdgcn_mfma_f32_16x16x32_bf16(pa[rf], vf, acc[rf][cf], 0, 0, 0);
            }
        }
    }

    // epilogue: ctx[b][t][h*64+dk] = acc / l
    const int b = bh >> 4, h = bh & 15;
#pragma unroll
    for (int rf = 0; rf < 2; rf++)
#pragma unroll
        for (int j = 0; j < 4; j++) {
            float inv = 1.0f / lrow[rf][j];
            int t = qbase + rf * 16 + l4 * 4 + j;
#pragma unroll
            for (int cf = 0; cf < 4; cf++) {
                int dk = cf * 16 + l15;
                ctx[((size_t)(b * TT + t)) * DD + h * 64 + dk] = f2bf(acc[rf][cf][j] * inv);
            }
        }
}

// ---------------------------------------------------------------- launch
extern "C" void kernel_launch(void* const* d_in, const int* in_sizes, int n_in,
                              void* d_out, int out_size, void* d_ws, size_t ws_size,
                              hipStream_t stream) {
    const float* x = (const float*)d_in[0];
    const float* Wq = (const float*)d_in[1];
    const float* Wk = (const float*)d_in[2];
    const float* Wv = (const float*)d_in[3];
    const float* Wo = (const float*)d_in[4];

    const int nX = BB * TT * DD;   // 8388608
    const int nW = DD * DD;        // 1048576
    const int nQ = BB * HH * TT * DKK;  // 8388608

    u16* xb = (u16*)d_ws;
    u16* wqb = xb + nX;
    u16* wkb = wqb + nW;
    u16* wvb = wkb + nW;
    u16* wob = wvb + nW;
    u16* Qb = wob + nW;
    u16* Kb = Qb + nQ;
    u16* Vtb = Kb + nQ;
    u16* ctxb = Vtb + nQ;
    // total: 5*8388608 + 4*1048576 elems * 2B ≈ 92.3 MB

    cast_f32_bf16<<<4096, 256, 0, stream>>>(x, xb, nX);
    cast_f32_bf16<<<1024, 256, 0, stream>>>(Wq, wqb, nW);
    cast_f32_bf16<<<1024, 256, 0, stream>>>(Wk, wkb, nW);
    cast_f32_bf16<<<1024, 256, 0, stream>>>(Wv, wvb, nW);
    cast_f32_bf16<<<1024, 256, 0, stream>>>(Wo, wob, nW);

    gemm_qkv<<<dim3((BB * TT) / 128, DD / 128, 3), 256, 0, stream>>>(xb, wqb, wkb, wvb, Qb, Kb, Vtb);

    attn_fwd<<<dim3(TT / 128, BB * HH), 256, 0, stream>>>(Qb, Kb, Vtb, ctxb);

    gemm_out<<<dim3((BB * TT) / 128, DD / 128), 256, 0, stream>>>(ctxb, wob, (float*)d_out);
}

// Round 3
// 248.454 us; speedup vs baseline: 1.3345x; 1.3345x over previous
//
#include <hip/hip_runtime.h>
#include <hip/hip_bf16.h>
#include <stdint.h>

#define BB 4
#define TT 2048
#define DD 1024
#define HH 16
#define DKK 64

typedef unsigned short u16;
typedef unsigned int u32;
typedef __bf16 bf16_t;
typedef bf16_t bf16x8 __attribute__((ext_vector_type(8)));
typedef float f32x4 __attribute__((ext_vector_type(4)));

__device__ __forceinline__ float bf2f(u16 u) {
    u32 x = ((u32)u) << 16;
    float f;
    __builtin_memcpy(&f, &x, 4);
    return f;
}
__device__ __forceinline__ u16 f2bf(float f) {
    u32 x;
    __builtin_memcpy(&x, &f, 4);
    x += 0x7fffu + ((x >> 16) & 1u);  // RNE truncate (no NaN inputs here)
    return (u16)(x >> 16);
}

// async global->LDS, 16B per lane; l must be the WAVE-UNIFORM base (lane*16 added by HW)
__device__ __forceinline__ void gll16(const u16* g, u16* l) {
    __builtin_amdgcn_global_load_lds((const __attribute__((address_space(1))) u32*)g,
                                     (__attribute__((address_space(3))) u32*)l, 16, 0, 0);
}

// ---------------------------------------------------------------- casts
__global__ void cast_f32_bf16(const float* __restrict__ in, u16* __restrict__ out, int n) {
    int i = (blockIdx.x * blockDim.x + threadIdx.x) * 4;
    int stride = gridDim.x * blockDim.x * 4;
    for (; i < n; i += stride) {
        float4 v = *reinterpret_cast<const float4*>(in + i);
        uint2 pk;
        pk.x = (u32)f2bf(v.x) | ((u32)f2bf(v.y) << 16);
        pk.y = (u32)f2bf(v.z) | ((u32)f2bf(v.w) << 16);
        *reinterpret_cast<uint2*>(out + i) = pk;
    }
}

// ---------------------------------------------------------------- GEMM core
// C[m][n] = sum_k A[m][k] * W[n][k]   (TN), M-tile 128, N-tile 128, BK=32
__device__ __forceinline__ void gemm_128_mainloop(const u16* __restrict__ A,
                                                  const u16* __restrict__ W,
                                                  u16* As, u16* Bs,
                                                  int m0, int n0, f32x4 acc[4][4]) {
    const int tid = threadIdx.x;
    const int lane = tid & 63;
    const int wid = tid >> 6;
    const int wr = (wid >> 1) * 64, wc = (wid & 1) * 64;
    const int l15 = lane & 15, l4 = lane >> 4;

    const f32x4 z4 = {0.f, 0.f, 0.f, 0.f};
#pragma unroll
    for (int i = 0; i < 4; i++)
#pragma unroll
        for (int j = 0; j < 4; j++) acc[i][j] = z4;

    const int r0 = tid >> 2;
    const int c0 = (tid & 3) * 8;

    for (int k0 = 0; k0 < DD; k0 += 32) {
        __syncthreads();
        gll16(A + (m0 + r0) * DD + k0 + c0, As + (wid * 64) * 8);
        gll16(A + (m0 + 64 + r0) * DD + k0 + c0, As + (256 + wid * 64) * 8);
        gll16(W + (n0 + r0) * DD + k0 + c0, Bs + (wid * 64) * 8);
        gll16(W + (n0 + 64 + r0) * DD + k0 + c0, Bs + (256 + wid * 64) * 8);
        asm volatile("s_waitcnt vmcnt(0)" ::: "memory");
        __syncthreads();

        bf16x8 af[4], bfr[4];
#pragma unroll
        for (int mi = 0; mi < 4; mi++)
            af[mi] = *reinterpret_cast<const bf16x8*>(As + (wr + mi * 16 + l15) * 32 + l4 * 8);
#pragma unroll
        for (int ni = 0; ni < 4; ni++)
            bfr[ni] = *reinterpret_cast<const bf16x8*>(Bs + (wc + ni * 16 + l15) * 32 + l4 * 8);
#pragma unroll
        for (int mi = 0; mi < 4; mi++)
#pragma unroll
            for (int ni = 0; ni < 4; ni++)
                acc[mi][ni] =
                    __builtin_amdgcn_mfma_f32_16x16x32_bf16(af[mi], bfr[ni], acc[mi][ni], 0, 0, 0);
    }
}

// z=0: Q  -> [b][h][t][dk] bf16 ; z=1: K same ; z=2: V -> [b][h][dk][t] bf16 (transposed)
__global__ __launch_bounds__(256) void gemm_qkv(const u16* __restrict__ xb,
                                                const u16* __restrict__ wq,
                                                const u16* __restrict__ wk,
                                                const u16* __restrict__ wv,
                                                u16* __restrict__ Qo, u16* __restrict__ Ko,
                                                u16* __restrict__ Vto) {
    __shared__ u16 As[128 * 32];
    __shared__ u16 Bs[128 * 32];
    const int z = blockIdx.z;
    const u16* W = (z == 0) ? wq : (z == 1) ? wk : wv;
    u16* dst = (z == 0) ? Qo : (z == 1) ? Ko : Vto;
    const int m0 = blockIdx.x * 128, n0 = blockIdx.y * 128;

    f32x4 acc[4][4];
    gemm_128_mainloop(xb, W, As, Bs, m0, n0, acc);

    const int lane = threadIdx.x & 63, wid = threadIdx.x >> 6;
    const int wr = (wid >> 1) * 64, wc = (wid & 1) * 64;
    const int l15 = lane & 15, l4 = lane >> 4;
#pragma unroll
    for (int mi = 0; mi < 4; mi++)
#pragma unroll
        for (int ni = 0; ni < 4; ni++)
#pragma unroll
            for (int j = 0; j < 4; j++) {
                int m = m0 + wr + mi * 16 + l4 * 4 + j;  // token
                int n = n0 + wc + ni * 16 + l15;          // feature e = h*64+dk
                int b = m >> 11, t = m & (TT - 1);
                int h = n >> 6, dk = n & 63;
                u16 v = f2bf(acc[mi][ni][j]);
                if (z < 2)
                    dst[((b * HH + h) * TT + t) * DKK + dk] = v;
                else
                    dst[((b * HH + h) * DKK + dk) * TT + t] = v;
            }
}

__global__ __launch_bounds__(256) void gemm_out(const u16* __restrict__ ctx,
                                                const u16* __restrict__ wo,
                                                float* __restrict__ out) {
    __shared__ u16 As[128 * 32];
    __shared__ u16 Bs[128 * 32];
    const int m0 = blockIdx.x * 128, n0 = blockIdx.y * 128;
    f32x4 acc[4][4];
    gemm_128_mainloop(ctx, wo, As, Bs, m0, n0, acc);

    const int lane = threadIdx.x & 63, wid = threadIdx.x >> 6;
    const int wr = (wid >> 1) * 64, wc = (wid & 1) * 64;
    const int l15 = lane & 15, l4 = lane >> 4;
#pragma unroll
    for (int mi = 0; mi < 4; mi++)
#pragma unroll
        for (int ni = 0; ni < 4; ni++)
#pragma unroll
            for (int j = 0; j < 4; j++) {
                int m = m0 + wr + mi * 16 + l4 * 4 + j;
                int n = n0 + wc + ni * 16 + l15;
                out[m * DD + n] = acc[mi][ni][j];
            }
}

// ---------------------------------------------------------------- flash attention v2
// Folded pairing: block (i, bh) handles q-tiles jA=i and jB=15-i (128 rows each),
// so every block has exactly 34 k-tile-units of MFMA work. 512 blocks, 2/CU.
// K/V double-buffered in LDS with counted vmcnt(4) prefetch (T3 2-phase recipe).

__device__ __forceinline__ void stage_kv(const u16* __restrict__ Kb, const u16* __restrict__ Vb,
                                         u16* Kd, u16* Vd, int kt, int tid, int wid) {
    int r = tid >> 3, cc = tid & 7;
    int cs = cc ^ (r & 7);
    gll16(Kb + (kt * 64 + r) * DKK + cs * 8, Kd + (wid * 64) * 8);
    gll16(Vb + r * TT + kt * 64 + cs * 8, Vd + (wid * 64) * 8);
    int r1 = 32 + r;
    int cs1 = cc ^ (r1 & 7);
    gll16(Kb + (kt * 64 + r1) * DKK + cs1 * 8, Kd + (256 + wid * 64) * 8);
    gll16(Vb + r1 * TT + kt * 64 + cs1 * 8, Vd + (256 + wid * 64) * 8);
}

// One 64-k-tile step for one 32-row q-tile owned by this wave.
__device__ __forceinline__ void attn_tile_step(const bf16x8 qf[2][2], f32x4 acc[2][4],
                                               float mrow[2][4], float lrow[2][4],
                                               const char* Kl, const char* Vl, char* Pw,
                                               int l15, int l4, bool domask, int kt, int qbase) {
    const f32x4 z4 = {0.f, 0.f, 0.f, 0.f};
    f32x4 s[2][4];
#pragma unroll
    for (int rf = 0; rf < 2; rf++)
#pragma unroll
        for (int cf = 0; cf < 4; cf++) s[rf][cf] = z4;

#pragma unroll
    for (int kc = 0; kc < 2; kc++) {
#pragma unroll
        for (int cf = 0; cf < 4; cf++) {
            int kr = cf * 16 + l15;
            int cw = (l4 + kc * 4) ^ (kr & 7);
            bf16x8 kf = *reinterpret_cast<const bf16x8*>(Kl + kr * 128 + cw * 16);
#pragma unroll
            for (int rf = 0; rf < 2; rf++)
                s[rf][cf] = __builtin_amdgcn_mfma_f32_16x16x32_bf16(qf[rf][kc], kf, s[rf][cf], 0, 0, 0);
        }
    }

    if (domask) {
#pragma unroll
        for (int rf = 0; rf < 2; rf++)
#pragma unroll
            for (int cf = 0; cf < 4; cf++)
#pragma unroll
                for (int j = 0; j < 4; j++) {
                    int kk = kt * 64 + cf * 16 + l15;
                    int qq = qbase + rf * 16 + l4 * 4 + j;
                    if (kk > qq) s[rf][cf][j] = -__builtin_huge_valf();
                }
    }

    // online softmax (row spans l15 lanes x 4 cf)
#pragma unroll
    for (int rf = 0; rf < 2; rf++) {
        float pm[4];
#pragma unroll
        for (int j = 0; j < 4; j++)
            pm[j] = fmaxf(fmaxf(s[rf][0][j], s[rf][1][j]), fmaxf(s[rf][2][j], s[rf][3][j]));
#pragma unroll
        for (int j = 0; j < 4; j++) {
            pm[j] = fmaxf(pm[j], __shfl_xor(pm[j], 1));
            pm[j] = fmaxf(pm[j], __shfl_xor(pm[j], 2));
            pm[j] = fmaxf(pm[j], __shfl_xor(pm[j], 4));
            pm[j] = fmaxf(pm[j], __shfl_xor(pm[j], 8));
        }
#pragma unroll
        for (int j = 0; j < 4; j++) {
            float mn = fmaxf(mrow[rf][j], pm[j]);
            float sc = __expf(mrow[rf][j] - mn);  // -inf - finite -> 0
            mrow[rf][j] = mn;
            float rs = 0.f;
#pragma unroll
            for (int cf = 0; cf < 4; cf++) {
                float p = __expf(s[rf][cf][j] - mn);
                s[rf][cf][j] = p;
                rs += p;
            }
            rs += __shfl_xor(rs, 1);
            rs += __shfl_xor(rs, 2);
            rs += __shfl_xor(rs, 4);
            rs += __shfl_xor(rs, 8);
            lrow[rf][j] = lrow[rf][j] * sc + rs;
#pragma unroll
            for (int cf = 0; cf < 4; cf++) acc[rf][cf][j] *= sc;
        }
    }

    // P -> per-wave LDS (swizzled), then PV
#pragma unroll
    for (int rf = 0; rf < 2; rf++)
#pragma unroll
        for (int cf = 0; cf < 4; cf++)
#pragma unroll
            for (int j = 0; j < 4; j++) {
                int r = rf * 16 + l4 * 4 + j;
                int col = cf * 16 + l15;
                int byte = r * 128 + (((col >> 3) ^ (r & 7)) << 4) + (col & 7) * 2;
                *reinterpret_cast<u16*>(Pw + byte) = f2bf(s[rf][cf][j]);
            }
    asm volatile("s_waitcnt lgkmcnt(0)" ::: "memory");

#pragma unroll
    for (int kc = 0; kc < 2; kc++) {
        bf16x8 pa[2];
#pragma unroll
        for (int rf = 0; rf < 2; rf++) {
            int r = rf * 16 + l15;
            int cw = (l4 + kc * 4) ^ (r & 7);
            pa[rf] = *reinterpret_cast<const bf16x8*>(Pw + r * 128 + cw * 16);
        }
#pragma unroll
        for (int cf = 0; cf < 4; cf++) {
            int vr = cf * 16 + l15;
            int vw = (l4 + kc * 4) ^ (vr & 7);
            bf16x8 vf = *reinterpret_cast<const bf16x8*>(Vl + vr * 128 + vw * 16);
#pragma unroll
            for (int rf = 0; rf < 2; rf++)
                acc[rf][cf] = __builtin_amdgcn_mfma_f32_16x16x32_bf16(pa[rf], vf, acc[rf][cf], 0, 0, 0);
        }
    }
}

__device__ __forceinline__ void load_qfrag(const u16* Qb, int qbase, int l15, int l4,
                                           bf16x8 qf[2][2]) {
#pragma unroll
    for (int rf = 0; rf < 2; rf++)
#pragma unroll
        for (int kc = 0; kc < 2; kc++) {
            const u16* p = Qb + (qbase + rf * 16 + l15) * DKK + kc * 32 + l4 * 8;
            union { uint4 u; u16 h[8]; } cv;
            cv.u = *reinterpret_cast<const uint4*>(p);
            u16 o[8];
#pragma unroll
            for (int e = 0; e < 8; e++) o[e] = f2bf(bf2f(cv.h[e]) * 0.125f);
            __builtin_memcpy(&qf[rf][kc], o, 16);
        }
}

__device__ __forceinline__ void write_ctx(u16* __restrict__ ctx, int b, int h, int qbase,
                                          int l15, int l4, const f32x4 acc[2][4],
                                          const float lrow[2][4]) {
#pragma unroll
    for (int rf = 0; rf < 2; rf++)
#pragma unroll
        for (int j = 0; j < 4; j++) {
            float inv = 1.0f / lrow[rf][j];
            int t = qbase + rf * 16 + l4 * 4 + j;
#pragma unroll
            for (int cf = 0; cf < 4; cf++) {
                int dk = cf * 16 + l15;
                ctx[((size_t)(b * TT + t)) * DD + h * 64 + dk] = f2bf(acc[rf][cf][j] * inv);
            }
        }
}

// grid: (8, B*H). blockIdx.x = i -> q-tiles jA=i, jB=15-i.
__global__ __launch_bounds__(256, 2) void attn_fwd(const u16* __restrict__ Qg,
                                                   const u16* __restrict__ Kg,
                                                   const u16* __restrict__ Vtg,
                                                   u16* __restrict__ ctx) {
    __shared__ u16 Kld[2][64 * 64];
    __shared__ u16 Vld[2][64 * 64];
    __shared__ u16 Pld[4][32 * 64];

    const int tid = threadIdx.x;
    const int lane = tid & 63, wid = tid >> 6;
    const int l15 = lane & 15, l4 = lane >> 4;
    const int bh = blockIdx.y;
    const int jA = blockIdx.x, jB = 15 - jA;
    const int qbaseA = jA * 128 + wid * 32;
    const int qbaseB = jB * 128 + wid * 32;
    const int nA = 2 * jA + 1 + (wid >> 1);  // per-wave causal k-tile count
    const int nB = 2 * jB + 1 + (wid >> 1);
    const int nkt = 2 * jB + 2;              // block trip count (max over waves)

    const u16* Qb = Qg + (size_t)bh * TT * DKK;
    const u16* Kb = Kg + (size_t)bh * TT * DKK;
    const u16* Vb = Vtg + (size_t)bh * DKK * TT;

    bf16x8 qfA[2][2], qfB[2][2];
    load_qfrag(Qb, qbaseA, l15, l4, qfA);
    load_qfrag(Qb, qbaseB, l15, l4, qfB);

    f32x4 accA[2][4], accB[2][4];
    const f32x4 z4 = {0.f, 0.f, 0.f, 0.f};
    float mrowA[2][4], lrowA[2][4], mrowB[2][4], lrowB[2][4];
#pragma unroll
    for (int rf = 0; rf < 2; rf++)
#pragma unroll
        for (int j = 0; j < 4; j++) {
            accA[rf][j] = z4; accB[rf][j] = z4;
            mrowA[rf][j] = -__builtin_huge_valf(); lrowA[rf][j] = 0.f;
            mrowB[rf][j] = -__builtin_huge_valf(); lrowB[rf][j] = 0.f;
        }

    char* Pw = reinterpret_cast<char*>(&Pld[wid][0]);

    stage_kv(Kb, Vb, Kld[0], Vld[0], 0, tid, wid);

    for (int kt = 0; kt < nkt; kt++) {
        if (kt + 1 < nkt) {
            stage_kv(Kb, Vb, Kld[(kt + 1) & 1], Vld[(kt + 1) & 1], kt + 1, tid, wid);
            asm volatile("s_waitcnt vmcnt(4)" ::: "memory");  // current tile's 4 loads done
        } else {
            asm volatile("s_waitcnt vmcnt(0)" ::: "memory");
        }
        __syncthreads();

        const char* Kl = reinterpret_cast<const char*>(Kld[kt & 1]);
        const char* Vl = reinterpret_cast<const char*>(Vld[kt & 1]);
        if (kt < nA)
            attn_tile_step(qfA, accA, mrowA, lrowA, Kl, Vl, Pw, l15, l4, kt == nA - 1, kt, qbaseA);
        if (kt < nB)
            attn_tile_step(qfB, accB, mrowB, lrowB, Kl, Vl, Pw, l15, l4, kt == nB - 1, kt, qbaseB);
        __syncthreads();
    }

    const int b = bh >> 4, h = bh & 15;
    write_ctx(ctx, b, h, qbaseA, l15, l4, accA, lrowA);
    write_ctx(ctx, b, h, qbaseB, l15, l4, accB, lrowB);
}

// ---------------------------------------------------------------- launch
extern "C" void kernel_launch(void* const* d_in, const int* in_sizes, int n_in,
                              void* d_out, int out_size, void* d_ws, size_t ws_size,
                              hipStream_t stream) {
    const float* x = (const float*)d_in[0];
    const float* Wq = (const float*)d_in[1];
    const float* Wk = (const float*)d_in[2];
    const float* Wv = (const float*)d_in[3];
    const float* Wo = (const float*)d_in[4];

    const int nX = BB * TT * DD;        // 8388608
    const int nW = DD * DD;             // 1048576
    const int nQ = BB * HH * TT * DKK;  // 8388608

    u16* xb = (u16*)d_ws;
    u16* wqb = xb + nX;
    u16* wkb = wqb + nW;
    u16* wvb = wkb + nW;
    u16* wob = wvb + nW;
    u16* Qb = wob + nW;
    u16* Kb = Qb + nQ;
    u16* Vtb = Kb + nQ;
    u16* ctxb = Vtb + nQ;

    cast_f32_bf16<<<4096, 256, 0, stream>>>(x, xb, nX);
    cast_f32_bf16<<<1024, 256, 0, stream>>>(Wq, wqb, nW);
    cast_f32_bf16<<<1024, 256, 0, stream>>>(Wk, wkb, nW);
    cast_f32_bf16<<<1024, 256, 0, stream>>>(Wv, wvb, nW);
    cast_f32_bf16<<<1024, 256, 0, stream>>>(Wo, wob, nW);

    gemm_qkv<<<dim3((BB * TT) / 128, DD / 128, 3), 256, 0, stream>>>(xb, wqb, wkb, wvb, Qb, Kb, Vtb);

    attn_fwd<<<dim3(8, BB * HH), 256, 0, stream>>>(Qb, Kb, Vtb, ctxb);

    gemm_out<<<dim3((BB * TT) / 128, DD / 128), 256, 0, stream>>>(ctxb, wob, (float*)d_out);
}